// Round 6
// baseline (1149.826 us; speedup 1.0000x reference)
//
#include <hip/hip_runtime.h>

typedef unsigned int u32;
typedef unsigned short u16;

#define DIM 128      // 4 factors * 32
#define ROW_DW 64    // fac: 64 dwords (bf16 pairs) per node row

__device__ __forceinline__ float bf1(u16 s){ return __uint_as_float(((u32)s) << 16); }
__device__ __forceinline__ u16 f2bf(float x){
  u32 u = __float_as_uint(x);
  return (u16)((u + 0x7fffu + ((u >> 16) & 1u)) >> 16);  // RNE
}

__global__ void zero_int_kernel(int* p, int n){
  int i = blockIdx.x * blockDim.x + threadIdx.x;
  if (i < n) p[i] = 0;
}

// wb[d][c] = W[f][d][k] + b[f][k],  c = f*32+k   (fp32 [128][128])
__global__ void prep_wb_kernel(const float* __restrict__ W, const float* __restrict__ B,
                               float* __restrict__ wb){
  int i = blockIdx.x * 256 + threadIdx.x;
  if (i >= DIM * DIM) return;
  int d = i >> 7, c = i & 127, f = c >> 5, k = c & 31;
  wb[d * DIM + c] = W[f * 4096 + d * 32 + k] + B[f * 32 + k];  // W:(4,128,32) b:(4,1,32)
}

// 256-thread blocks, one node per wave. Lane l owns cols {2l, 2l+1}; factor = l>>4.
// emb row staged in registers (float2/lane) and broadcast via shuffles.
__global__ void fac_kernel(const float* __restrict__ emb, const float* __restrict__ wb,
                           u32* __restrict__ fac, int N){
  int lane = threadIdx.x & 63;
  int n = blockIdx.x * 4 + (threadIdx.x >> 6);
  if (n >= N) return;
  const float2* ep = (const float2*)(emb + (size_t)n * DIM);   // 64 float2 = 128 floats
  float2 ev = ep[lane];                                        // lane holds dims 2l,2l+1
  const float2* wp = (const float2*)wb;                        // [128][64] float2
  float a0 = 0.f, a1 = 0.f;
#pragma unroll 4
  for (int j = 0; j < 64; ++j) {
    float r0 = __shfl(ev.x, j), r1 = __shfl(ev.y, j);          // dims 2j, 2j+1
    float2 w0 = wp[(2 * j) * 64 + lane];
    float2 w1 = wp[(2 * j + 1) * 64 + lane];
    a0 = fmaf(r0, w0.x, a0); a1 = fmaf(r0, w0.y, a1);
    a0 = fmaf(r1, w1.x, a0); a1 = fmaf(r1, w1.y, a1);
  }
  a0 = a0 > 0.f ? a0 : 0.2f * a0;                  // leaky_relu(0.2)
  a1 = a1 > 0.f ? a1 : 0.2f * a1;
  float ss = a0 * a0 + a1 * a1;                    // l2 over this factor's 32 cols
  ss += __shfl_xor(ss, 1); ss += __shfl_xor(ss, 2);
  ss += __shfl_xor(ss, 4); ss += __shfl_xor(ss, 8);
  float inv = 1.0f / fmaxf(sqrtf(ss), 1e-12f);
  fac[(size_t)n * ROW_DW + lane] = (u32)f2bf(a0 * inv) | ((u32)f2bf(a1 * inv) << 16);
}

__global__ void hist_kernel(const int* __restrict__ row, int* __restrict__ cnt, int E, int N){
  int stride = gridDim.x * blockDim.x;
  for (int e = blockIdx.x * blockDim.x + threadIdx.x; e < E; e += stride) {
    int r = row[e];
    if ((u32)r < (u32)N) atomicAdd(&cnt[r], 1);
  }
}

// single-block (256 threads) exclusive scan of cnt[0..N) -> offs[0..N]
__global__ void scan_kernel(const int* __restrict__ cnt, int* __restrict__ offs, int N){
  __shared__ int sh[256];
  int tid = threadIdx.x;
  int per = (N + 255) >> 8;
  int beg = tid * per; if (beg > N) beg = N;
  int end = beg + per; if (end > N) end = N;
  int s = 0;
  for (int i = beg; i < end; ++i) s += cnt[i];
  sh[tid] = s;
  __syncthreads();
  for (int off = 1; off < 256; off <<= 1) {
    int v = (tid >= off) ? sh[tid - off] : 0;
    __syncthreads();
    sh[tid] += v;
    __syncthreads();
  }
  int run = (tid == 0) ? 0 : sh[tid - 1];
  for (int i = beg; i < end; ++i) { offs[i] = run; run += cnt[i]; }
  if (tid == 255) offs[N] = run;
}

__global__ void copy_kernel(const int* __restrict__ src, int* __restrict__ dst, int N){
  int i = blockIdx.x * blockDim.x + threadIdx.x;
  if (i < N) dst[i] = src[i];
}

__global__ void scatter_kernel(const int* __restrict__ row, const int* __restrict__ col,
                               int* __restrict__ cur, int* __restrict__ ccol, int E, int N){
  int stride = gridDim.x * blockDim.x;
  for (int e = blockIdx.x * blockDim.x + threadIdx.x; e < E; e += stride) {
    int r = row[e];
    if ((u32)r >= (u32)N) continue;
    int pos = atomicAdd(&cur[r], 1);
    if ((u32)pos < (u32)E) ccol[pos] = col[e];
  }
}

// 256-thread blocks, one node per wave: acc = fac[n] (bf16); per edge (n->c):
// 4 factor dots vs head, softmax over factors, acc += p * fac[c];
// out[n] = l2norm_f(acc) written fp32. head is fp32 (fac32 pass uses fac-derived
// floats; see head unpack flag).
__global__ void edge_kernel(const void* __restrict__ headp, int head_is_bf16,
                            const u32* __restrict__ fac, const int* __restrict__ offs,
                            const int* __restrict__ ccol, float* __restrict__ outp,
                            int N, int E){
  int lane = threadIdx.x & 63;
  int n = blockIdx.x * 4 + (threadIdx.x >> 6);
  if (n >= N) return;
  float h0, h1;
  if (head_is_bf16) {
    u32 hv = ((const u32*)headp)[(size_t)n * ROW_DW + lane];
    h0 = bf1((u16)hv); h1 = bf1((u16)(hv >> 16));
  } else {
    float2 hv = ((const float2*)headp)[(size_t)n * ROW_DW + lane];
    h0 = hv.x; h1 = hv.y;
  }
  u32 fv = fac[(size_t)n * ROW_DW + lane];
  float a0 = bf1((u16)fv), a1 = bf1((u16)(fv >> 16));
  int beg = offs[n], end = offs[n + 1];
  if (beg < 0) beg = 0;
  if (end > E) end = E;
  if (end < beg) end = beg;
  u32 tv = 0u;
  if (beg < end) {
    int c0 = ccol[beg];
    tv = ((u32)c0 < (u32)N) ? fac[(size_t)c0 * ROW_DW + lane] : 0u;
  }
  for (int e = beg; e < end; ++e) {
    u32 tc = tv;
    if (e + 1 < end) {
      int c1 = ccol[e + 1];
      tv = ((u32)c1 < (u32)N) ? fac[(size_t)c1 * ROW_DW + lane] : 0u;  // prefetch
    }
    float t0 = bf1((u16)tc), t1 = bf1((u16)(tc >> 16));
    float d = fmaf(h0, t0, h1 * t1);
    d += __shfl_xor(d, 1); d += __shfl_xor(d, 2);  // 32 comps within quad
    d += __shfl_xor(d, 4); d += __shfl_xor(d, 8);
    float dB = __shfl_xor(d, 16);                  // other three factor dots
    float dC = __shfl_xor(d, 32);
    float dD = __shfl_xor(dB, 32);
    float mx = fmaxf(fmaxf(d, dB), fmaxf(dC, dD));
    float e0 = __expf(d - mx);
    float es = e0 + __expf(dB - mx) + __expf(dC - mx) + __expf(dD - mx);
    float p = e0 / es;                             // softmax over factors (axis=0)
    a0 = fmaf(p, t0, a0); a1 = fmaf(p, t1, a1);
  }
  float ss = a0 * a0 + a1 * a1;
  ss += __shfl_xor(ss, 1); ss += __shfl_xor(ss, 2);
  ss += __shfl_xor(ss, 4); ss += __shfl_xor(ss, 8);
  float inv = 1.0f / fmaxf(sqrtf(ss), 1e-12f);
  ((float2*)outp)[(size_t)n * ROW_DW + lane] = make_float2(a0 * inv, a1 * inv);
}

extern "C" void kernel_launch(void* const* d_in, const int* in_sizes, int n_in,
                              void* d_out, int out_size, void* d_ws, size_t ws_size,
                              hipStream_t stream) {
  // Map inputs by element-count signature (robust to ordering): emb = largest,
  // W = 16384, b = 128, remaining two (original order) = row, col.
  int ie = 0, iw = 1, ib = 2, ir = 3, ic = 4;
  if (n_in == 5) {
    int best = -1, besti = 0;
    for (int i = 0; i < 5; ++i) if (in_sizes[i] > best) { best = in_sizes[i]; besti = i; }
    ie = besti; iw = -1; ib = -1; ir = -1; ic = -1;
    for (int i = 0; i < 5; ++i) {
      if (i == ie) continue;
      if (in_sizes[i] == 16384 && iw < 0) iw = i;
      else if (in_sizes[i] == 128 && ib < 0) ib = i;
      else if (ir < 0) ir = i;
      else ic = i;
    }
    if (iw < 0 || ib < 0 || ir < 0 || ic < 0) { ie = 0; iw = 1; ib = 2; ir = 3; ic = 4; }
  }
  const float* emb = (const float*)d_in[ie];   // (N,128) fp32
  const float* W   = (const float*)d_in[iw];   // (4,128,32) fp32
  const float* B   = (const float*)d_in[ib];   // (4,1,32) fp32
  const int* row   = (const int*)d_in[ir];     // (E,)
  const int* col   = (const int*)d_in[ic];     // (E,)
  int N = in_sizes[ie] / DIM;
  int E = in_sizes[ir];
  float* out = (float*)d_out;                  // (N,128) fp32

  // workspace (~33.7 MB): cnt | offs | cur | ccol | wb | fac
  char* ws = (char*)d_ws;
  int* cnt   = (int*)ws;                       // N
  int* offs  = cnt + N;                        // N+1
  int* cur   = offs + N + 1;                   // N
  int* ccol  = cur + N;                        // E
  float* wb  = (float*)(ccol + E);             // 128*128 fp32
  u32* fac   = (u32*)(wb + DIM * DIM);         // N*64 u32 (bf16 pairs)

  prep_wb_kernel<<<(DIM * DIM + 255) / 256, 256, 0, stream>>>(W, B, wb);
  fac_kernel<<<(N + 3) / 4, 256, 0, stream>>>(emb, wb, fac, N);
  zero_int_kernel<<<(N + 255) / 256, 256, 0, stream>>>(cnt, N);
  hist_kernel<<<1024, 256, 0, stream>>>(row, cnt, E, N);
  scan_kernel<<<1, 256, 0, stream>>>(cnt, offs, N);
  copy_kernel<<<(N + 255) / 256, 256, 0, stream>>>(offs, cur, N);
  scatter_kernel<<<1024, 256, 0, stream>>>(row, col, cur, ccol, E, N);
  // iter 1: head = fac (bf16) -> d_out (fp32)
  // iter 2: head = d_out (fp32) -> d_out in-place (block reads only row n, writes row n)
  edge_kernel<<<(N + 3) / 4, 256, 0, stream>>>(fac, 1, fac, offs, ccol, out, N, E);
  edge_kernel<<<(N + 3) / 4, 256, 0, stream>>>(out, 0, fac, offs, ccol, out, N, E);
}

// Round 7
// 656.318 us; speedup vs baseline: 1.7519x; 1.7519x over previous
//
#include <hip/hip_runtime.h>

typedef unsigned int u32;
typedef unsigned short u16;
typedef __attribute__((ext_vector_type(8))) short short8;   // 8 bf16 (4 VGPRs)
typedef __attribute__((ext_vector_type(4))) float f32x4;    // MFMA acc

#define DIM 128      // 4 factors * 32 cols
#define ROW_DW 64    // fac row = 64 dwords (bf16 pairs)

__device__ __forceinline__ float bf_lo(u32 u){ return __uint_as_float(u << 16); }
__device__ __forceinline__ float bf_hi(u32 u){ return __uint_as_float(u & 0xffff0000u); }
__device__ __forceinline__ u16 f2bf(float x){
  u32 u = __float_as_uint(x);
  return (u16)((u + 0x7fffu + ((u >> 16) & 1u)) >> 16);  // RNE
}

__global__ void zero_int_kernel(int* p, int n){
  int i = blockIdx.x * blockDim.x + threadIdx.x;
  if (i < n) p[i] = 0;
}

// B fragments for mfma_f32_16x16x32_bf16, layout [kt][ct][lane][j]:
// frag = bf16( W[f][d][k] + b[f][k] ) at d = kt*32+(lane>>4)*8+j, c = ct*16+(lane&15)
__global__ void prep_bfrag_kernel(const float* __restrict__ W, const float* __restrict__ B,
                                  u16* __restrict__ frag){
  int i = blockIdx.x * 256 + threadIdx.x;       // 4*8*64*8 = 16384
  if (i >= 16384) return;
  int j = i & 7, lane = (i >> 3) & 63, ct = (i >> 9) & 7, kt = i >> 12;
  int d = kt * 32 + (lane >> 4) * 8 + j;
  int c = ct * 16 + (lane & 15);
  int f = c >> 5, k = c & 31;
  frag[i] = f2bf(W[f * 4096 + d * 32 + k] + B[f * 32 + k]);  // W:(4,128,32) b:(4,1,32)
}

// fac = l2norm_f(leaky(emb @ wb)) via MFMA. Wave handles 16 nodes x 128 cols.
// A[m=lane&15][k=quad*8+j] from emb (fp32->bf16); B from prepped frags;
// D: row=(quad)*4+reg, col=ct*16+(lane&15). fac stored u16 [node][col].
__global__ __launch_bounds__(256) void fac_mfma_kernel(const float* __restrict__ emb,
                                                       const short8* __restrict__ bfrag,
                                                       u16* __restrict__ fac, int N){
  int lane = threadIdx.x & 63;
  int nb = blockIdx.x * 64 + (threadIdx.x >> 6) * 16;
  if (nb >= N) return;
  int quad = lane >> 4, lo = lane & 15;
  int arow = nb + lo; if (arow >= N) arow = N - 1;
  const float* ap = emb + (size_t)arow * DIM + quad * 8;
  f32x4 acc[8];
#pragma unroll
  for (int ct = 0; ct < 8; ++ct) acc[ct] = (f32x4){0.f, 0.f, 0.f, 0.f};
#pragma unroll
  for (int kt = 0; kt < 4; ++kt) {
    float4 e0 = *(const float4*)(ap + kt * 32);
    float4 e1 = *(const float4*)(ap + kt * 32 + 4);
    short8 afr;
    afr[0] = (short)f2bf(e0.x); afr[1] = (short)f2bf(e0.y);
    afr[2] = (short)f2bf(e0.z); afr[3] = (short)f2bf(e0.w);
    afr[4] = (short)f2bf(e1.x); afr[5] = (short)f2bf(e1.y);
    afr[6] = (short)f2bf(e1.z); afr[7] = (short)f2bf(e1.w);
#pragma unroll
    for (int ct = 0; ct < 8; ++ct) {
      short8 bfr = bfrag[(kt * 8 + ct) * 64 + lane];
      acc[ct] = __builtin_amdgcn_mfma_f32_16x16x32_bf16(afr, bfr, acc[ct], 0, 0, 0);
    }
  }
  // epilogue: leaky_relu then per-(node,factor) l2norm over 32 cols
  float v[8][4];
#pragma unroll
  for (int ct = 0; ct < 8; ++ct)
#pragma unroll
    for (int i = 0; i < 4; ++i) {
      float x = acc[ct][i];
      v[ct][i] = x > 0.f ? x : 0.2f * x;
    }
  float inv[4][4];   // [i][f]
#pragma unroll
  for (int i = 0; i < 4; ++i)
#pragma unroll
    for (int f = 0; f < 4; ++f) {
      float ss = v[2 * f][i] * v[2 * f][i] + v[2 * f + 1][i] * v[2 * f + 1][i];
      ss += __shfl_xor(ss, 1); ss += __shfl_xor(ss, 2);
      ss += __shfl_xor(ss, 4); ss += __shfl_xor(ss, 8);   // 16 lanes of this quad
      inv[i][f] = 1.0f / fmaxf(sqrtf(ss), 1e-12f);
    }
#pragma unroll
  for (int i = 0; i < 4; ++i) {
    int node = nb + quad * 4 + i;
    if (node >= N) continue;
#pragma unroll
    for (int ct = 0; ct < 8; ++ct)
      fac[(size_t)node * DIM + ct * 16 + lo] = f2bf(v[ct][i] * inv[i][ct >> 1]);
  }
}

__global__ void hist_kernel(const int* __restrict__ row, int* __restrict__ cnt, int E, int N){
  int stride = gridDim.x * blockDim.x;
  for (int e = blockIdx.x * blockDim.x + threadIdx.x; e < E; e += stride) {
    int r = row[e];
    if ((u32)r < (u32)N) atomicAdd(&cnt[r], 1);
  }
}

// single-block (1024 threads) exclusive scan of cnt[0..N) -> offs[0..N]
__global__ __launch_bounds__(1024) void scan_kernel(const int* __restrict__ cnt,
                                                    int* __restrict__ offs, int N){
  __shared__ int sh[1024];
  int tid = threadIdx.x;
  int per = (N + 1023) >> 10;
  int beg = tid * per; if (beg > N) beg = N;
  int end = beg + per; if (end > N) end = N;
  int s = 0;
  for (int i = beg; i < end; ++i) s += cnt[i];
  sh[tid] = s;
  __syncthreads();
  for (int off = 1; off < 1024; off <<= 1) {
    int v = (tid >= off) ? sh[tid - off] : 0;
    __syncthreads();
    sh[tid] += v;
    __syncthreads();
  }
  int run = (tid == 0) ? 0 : sh[tid - 1];
  for (int i = beg; i < end; ++i) { offs[i] = run; run += cnt[i]; }
  if (tid == 1023) offs[N] = run;
}

__global__ void copy_kernel(const int* __restrict__ src, int* __restrict__ dst, int N){
  int i = blockIdx.x * blockDim.x + threadIdx.x;
  if (i < N) dst[i] = src[i];
}

__global__ void scatter_kernel(const int* __restrict__ row, const int* __restrict__ col,
                               int* __restrict__ cur, int* __restrict__ ccol, int E, int N){
  int stride = gridDim.x * blockDim.x;
  for (int e = blockIdx.x * blockDim.x + threadIdx.x; e < E; e += stride) {
    int r = row[e];
    if ((u32)r >= (u32)N) continue;
    int pos = atomicAdd(&cur[r], 1);
    if ((u32)pos < (u32)E) ccol[pos] = col[e];
  }
}

// One wave per node; each 16-lane quad owns one edge (4 in flight).
// Lane (q,k): cols [8k, 8k+8). Per edge: 8-FMA partial dot -> 2 shfl reduce
// (4-lane group = one factor) -> 3 shfl gather (all 4 factor dots) -> softmax
// -> acc += p*tail. Epilogue: cross-quad merge, +fac[n], per-factor l2norm.
__global__ __launch_bounds__(256) void edge_kernel(const void* __restrict__ headp,
                                                   int head_is_bf16,
                                                   const u32* __restrict__ fac,
                                                   const int* __restrict__ offs,
                                                   const int* __restrict__ ccol,
                                                   float* __restrict__ outp, int N, int E){
  int lane = threadIdx.x & 63;
  int n = blockIdx.x * 4 + (threadIdx.x >> 6);
  if (n >= N) return;
  int q = lane >> 4, k = lane & 15;
  float h[8];
  if (head_is_bf16) {
    uint4 hv = *(const uint4*)((const u32*)headp + (size_t)n * ROW_DW + 4 * k);
    h[0] = bf_lo(hv.x); h[1] = bf_hi(hv.x); h[2] = bf_lo(hv.y); h[3] = bf_hi(hv.y);
    h[4] = bf_lo(hv.z); h[5] = bf_hi(hv.z); h[6] = bf_lo(hv.w); h[7] = bf_hi(hv.w);
  } else {
    const float* hp = (const float*)headp + (size_t)n * DIM + 8 * k;
    float4 x0 = *(const float4*)hp, x1 = *(const float4*)(hp + 4);
    h[0] = x0.x; h[1] = x0.y; h[2] = x0.z; h[3] = x0.w;
    h[4] = x1.x; h[5] = x1.y; h[6] = x1.z; h[7] = x1.w;
  }
  float a[8];
#pragma unroll
  for (int j = 0; j < 8; ++j) a[j] = 0.f;
  int beg = offs[n], end = offs[n + 1];
  if (beg < 0) beg = 0;
  if (end > E) end = E;
  for (int e0 = beg; e0 < end; e0 += 4) {
    int e = e0 + q;
    int valid = (e < end) ? 1 : 0;
    int c = valid ? ccol[e] : 0;
    if ((u32)c >= (u32)N) c = 0;
    uint4 tv = *(const uint4*)(fac + (size_t)c * ROW_DW + 4 * k);
    float t[8];
    t[0] = bf_lo(tv.x); t[1] = bf_hi(tv.x); t[2] = bf_lo(tv.y); t[3] = bf_hi(tv.y);
    t[4] = bf_lo(tv.z); t[5] = bf_hi(tv.z); t[6] = bf_lo(tv.w); t[7] = bf_hi(tv.w);
    float dp = 0.f;
#pragma unroll
    for (int j = 0; j < 8; ++j) dp = fmaf(h[j], t[j], dp);
    dp += __shfl_xor(dp, 1); dp += __shfl_xor(dp, 2);   // dot of factor k>>2, edge q
    float d1 = __shfl_xor(dp, 4);
    float d2 = __shfl_xor(dp, 8);
    float d3 = __shfl_xor(d1, 8);                       // all 4 factor dots (unordered)
    float mx = fmaxf(fmaxf(dp, d1), fmaxf(d2, d3));
    float ex = __expf(dp - mx);
    float es = ex + __expf(d1 - mx) + __expf(d2 - mx) + __expf(d3 - mx);
    float p = valid ? (ex / es) : 0.f;                  // own factor's softmax weight
#pragma unroll
    for (int j = 0; j < 8; ++j) a[j] = fmaf(p, t[j], a[j]);
  }
#pragma unroll
  for (int j = 0; j < 8; ++j) {                         // merge the 4 edge-slots
    a[j] += __shfl_xor(a[j], 16);
    a[j] += __shfl_xor(a[j], 32);
  }
  uint4 fv = *(const uint4*)(fac + (size_t)n * ROW_DW + 4 * k);
  a[0] += bf_lo(fv.x); a[1] += bf_hi(fv.x); a[2] += bf_lo(fv.y); a[3] += bf_hi(fv.y);
  a[4] += bf_lo(fv.z); a[5] += bf_hi(fv.z); a[6] += bf_lo(fv.w); a[7] += bf_hi(fv.w);
  float ss = 0.f;
#pragma unroll
  for (int j = 0; j < 8; ++j) ss = fmaf(a[j], a[j], ss);
  ss += __shfl_xor(ss, 1); ss += __shfl_xor(ss, 2);     // per-factor (4-lane group)
  float inv = 1.0f / fmaxf(sqrtf(ss), 1e-12f);
  if (q == 0) {
    float* op = outp + (size_t)n * DIM + 8 * k;
    *(float4*)op       = make_float4(a[0] * inv, a[1] * inv, a[2] * inv, a[3] * inv);
    *(float4*)(op + 4) = make_float4(a[4] * inv, a[5] * inv, a[6] * inv, a[7] * inv);
  }
}

extern "C" void kernel_launch(void* const* d_in, const int* in_sizes, int n_in,
                              void* d_out, int out_size, void* d_ws, size_t ws_size,
                              hipStream_t stream) {
  int ie = 0, iw = 1, ib = 2, ir = 3, ic = 4;
  if (n_in == 5) {
    int best = -1, besti = 0;
    for (int i = 0; i < 5; ++i) if (in_sizes[i] > best) { best = in_sizes[i]; besti = i; }
    ie = besti; iw = -1; ib = -1; ir = -1; ic = -1;
    for (int i = 0; i < 5; ++i) {
      if (i == ie) continue;
      if (in_sizes[i] == 16384 && iw < 0) iw = i;
      else if (in_sizes[i] == 128 && ib < 0) ib = i;
      else if (ir < 0) ir = i;
      else ic = i;
    }
    if (iw < 0 || ib < 0 || ir < 0 || ic < 0) { ie = 0; iw = 1; ib = 2; ir = 3; ic = 4; }
  }
  const float* emb = (const float*)d_in[ie];   // (N,128) fp32
  const float* W   = (const float*)d_in[iw];   // (4,128,32) fp32
  const float* B   = (const float*)d_in[ib];   // (4,1,32) fp32
  const int* row   = (const int*)d_in[ir];     // (E,)
  const int* col   = (const int*)d_in[ic];     // (E,)
  int N = in_sizes[ie] / DIM;
  int E = in_sizes[ir];
  float* out = (float*)d_out;                  // (N,128) fp32

  // workspace (~33.3 MB): fac | bfrag | cnt | offs | cur | ccol
  char* ws = (char*)d_ws;
  u16* fac   = (u16*)ws;                       // N*128 u16 (16B aligned)
  u16* bfrag = fac + (size_t)N * DIM;          // 16384 u16 (32 KB)
  int* cnt   = (int*)(bfrag + 16384);          // N
  int* offs  = cnt + N;                        // N+1
  int* cur   = offs + N + 1;                   // N
  int* ccol  = cur + N;                        // E

  prep_bfrag_kernel<<<64, 256, 0, stream>>>(W, B, bfrag);
  fac_mfma_kernel<<<(N + 63) / 64, 256, 0, stream>>>(emb, (const short8*)bfrag, fac, N);
  zero_int_kernel<<<(N + 255) / 256, 256, 0, stream>>>(cnt, N);
  hist_kernel<<<1024, 256, 0, stream>>>(row, cnt, E, N);
  scan_kernel<<<1, 1024, 0, stream>>>(cnt, offs, N);
  copy_kernel<<<(N + 255) / 256, 256, 0, stream>>>(offs, cur, N);
  scatter_kernel<<<1024, 256, 0, stream>>>(row, col, cur, ccol, E, N);
  // iter 1: head = fac (bf16) -> d_out (fp32); iter 2: head = d_out -> d_out in-place
  edge_kernel<<<(N + 3) / 4, 256, 0, stream>>>(fac, 1, (const u32*)fac, offs, ccol, out, N, E);
  edge_kernel<<<(N + 3) / 4, 256, 0, stream>>>(out, 0, (const u32*)fac, offs, ccol, out, N, E);
}

// Round 8
// 509.884 us; speedup vs baseline: 2.2551x; 1.2872x over previous
//
#include <hip/hip_runtime.h>

typedef unsigned int u32;
typedef unsigned short u16;
typedef __attribute__((ext_vector_type(8))) short short8;   // 8 bf16 (4 VGPRs)
typedef __attribute__((ext_vector_type(4))) float f32x4;    // MFMA acc

#define DIM 128      // 4 factors * 32 cols
#define ROW_DW 64    // fac row = 64 dwords (bf16 pairs)

__device__ __forceinline__ float bf_lo(u32 u){ return __uint_as_float(u << 16); }
__device__ __forceinline__ float bf_hi(u32 u){ return __uint_as_float(u & 0xffff0000u); }
__device__ __forceinline__ u16 f2bf(float x){
  u32 u = __float_as_uint(x);
  return (u16)((u + 0x7fffu + ((u >> 16) & 1u)) >> 16);  // RNE
}

__global__ void zero_int_kernel(int* p, int n){
  int i = blockIdx.x * blockDim.x + threadIdx.x;
  if (i < n) p[i] = 0;
}

// B fragments for mfma_f32_16x16x32_bf16, layout [kt][ct][lane][j]:
// frag = bf16( W[f][d][k] + b[f][k] ) at d = kt*32+(lane>>4)*8+j, c = ct*16+(lane&15)
__global__ void prep_bfrag_kernel(const float* __restrict__ W, const float* __restrict__ B,
                                  u16* __restrict__ frag){
  int i = blockIdx.x * 256 + threadIdx.x;       // 4*8*64*8 = 16384
  if (i >= 16384) return;
  int j = i & 7, lane = (i >> 3) & 63, ct = (i >> 9) & 7, kt = i >> 12;
  int d = kt * 32 + (lane >> 4) * 8 + j;
  int c = ct * 16 + (lane & 15);
  int f = c >> 5, k = c & 31;
  frag[i] = f2bf(W[f * 4096 + d * 32 + k] + B[f * 32 + k]);  // W:(4,128,32) b:(4,1,32)
}

// fac = l2norm_f(leaky(emb @ wb)) via MFMA. Wave handles 16 nodes x 128 cols.
__global__ __launch_bounds__(256) void fac_mfma_kernel(const float* __restrict__ emb,
                                                       const short8* __restrict__ bfrag,
                                                       u16* __restrict__ fac, int N){
  int lane = threadIdx.x & 63;
  int nb = blockIdx.x * 64 + (threadIdx.x >> 6) * 16;
  if (nb >= N) return;
  int quad = lane >> 4, lo = lane & 15;
  int arow = nb + lo; if (arow >= N) arow = N - 1;
  const float* ap = emb + (size_t)arow * DIM + quad * 8;
  f32x4 acc[8];
#pragma unroll
  for (int ct = 0; ct < 8; ++ct) acc[ct] = (f32x4){0.f, 0.f, 0.f, 0.f};
#pragma unroll
  for (int kt = 0; kt < 4; ++kt) {
    float4 e0 = *(const float4*)(ap + kt * 32);
    float4 e1 = *(const float4*)(ap + kt * 32 + 4);
    short8 afr;
    afr[0] = (short)f2bf(e0.x); afr[1] = (short)f2bf(e0.y);
    afr[2] = (short)f2bf(e0.z); afr[3] = (short)f2bf(e0.w);
    afr[4] = (short)f2bf(e1.x); afr[5] = (short)f2bf(e1.y);
    afr[6] = (short)f2bf(e1.z); afr[7] = (short)f2bf(e1.w);
#pragma unroll
    for (int ct = 0; ct < 8; ++ct) {
      short8 bfr = bfrag[(kt * 8 + ct) * 64 + lane];
      acc[ct] = __builtin_amdgcn_mfma_f32_16x16x32_bf16(afr, bfr, acc[ct], 0, 0, 0);
    }
  }
  float v[8][4];
#pragma unroll
  for (int ct = 0; ct < 8; ++ct)
#pragma unroll
    for (int i = 0; i < 4; ++i) {
      float x = acc[ct][i];
      v[ct][i] = x > 0.f ? x : 0.2f * x;
    }
  float inv[4][4];   // [i][f]
#pragma unroll
  for (int i = 0; i < 4; ++i)
#pragma unroll
    for (int f = 0; f < 4; ++f) {
      float ss = v[2 * f][i] * v[2 * f][i] + v[2 * f + 1][i] * v[2 * f + 1][i];
      ss += __shfl_xor(ss, 1); ss += __shfl_xor(ss, 2);
      ss += __shfl_xor(ss, 4); ss += __shfl_xor(ss, 8);
      inv[i][f] = 1.0f / fmaxf(sqrtf(ss), 1e-12f);
    }
#pragma unroll
  for (int i = 0; i < 4; ++i) {
    int node = nb + quad * 4 + i;
    if (node >= N) continue;
#pragma unroll
    for (int ct = 0; ct < 8; ++ct)
      fac[(size_t)node * DIM + ct * 16 + lo] = f2bf(v[ct][i] * inv[i][ct >> 1]);
  }
}

__global__ void hist_kernel(const int* __restrict__ row, int* __restrict__ cnt, int E, int N){
  int stride = gridDim.x * blockDim.x;
  for (int e = blockIdx.x * blockDim.x + threadIdx.x; e < E; e += stride) {
    int r = row[e];
    if ((u32)r < (u32)N) atomicAdd(&cnt[r], 1);
  }
}

// ---- 3-phase exclusive scan of cnt[0..N) -> offs[0..N], bsum scratch ----
// phase 1: each block scans 1024 elements (4/thread), writes local exclusive
// scan to offs and its block total to bsum[blk].
__global__ __launch_bounds__(256) void scan1_kernel(const int* __restrict__ cnt,
                                                    int* __restrict__ offs,
                                                    int* __restrict__ bsum, int N){
  __shared__ int sh[256];
  int tid = threadIdx.x;
  int idx = blockIdx.x * 1024 + tid * 4;
  int v0 = (idx     < N) ? cnt[idx]     : 0;
  int v1 = (idx + 1 < N) ? cnt[idx + 1] : 0;
  int v2 = (idx + 2 < N) ? cnt[idx + 2] : 0;
  int v3 = (idx + 3 < N) ? cnt[idx + 3] : 0;
  sh[tid] = v0 + v1 + v2 + v3;
  __syncthreads();
  for (int off = 1; off < 256; off <<= 1) {
    int v = (tid >= off) ? sh[tid - off] : 0;
    __syncthreads();
    sh[tid] += v;
    __syncthreads();
  }
  int ex = (tid == 0) ? 0 : sh[tid - 1];
  if (tid == 255) bsum[blockIdx.x] = sh[255];
  if (idx     < N) offs[idx]     = ex;
  if (idx + 1 < N) offs[idx + 1] = ex + v0;
  if (idx + 2 < N) offs[idx + 2] = ex + v0 + v1;
  if (idx + 3 < N) offs[idx + 3] = ex + v0 + v1 + v2;
}

// phase 2: one block exclusive-scans bsum[0..B), appends total at bsum[B]
__global__ __launch_bounds__(1024) void scan2_kernel(int* __restrict__ bsum, int B){
  __shared__ int sh[1024];
  int tid = threadIdx.x;
  sh[tid] = (tid < B) ? bsum[tid] : 0;
  __syncthreads();
  for (int off = 1; off < 1024; off <<= 1) {
    int v = (tid >= off) ? sh[tid - off] : 0;
    __syncthreads();
    sh[tid] += v;
    __syncthreads();
  }
  if (tid < B) bsum[tid] = (tid == 0) ? 0 : sh[tid - 1];
  if (tid == B - 1) bsum[B] = sh[tid];
}

// phase 3: add block offsets; fused copy to cur; writes offs[N]
__global__ void scan3_kernel(int* __restrict__ offs, const int* __restrict__ bsum,
                             int* __restrict__ cur, int N, int B){
  int i = blockIdx.x * blockDim.x + threadIdx.x;
  if (i < N) {
    int v = offs[i] + bsum[i >> 10];
    offs[i] = v;
    cur[i] = v;
  }
  if (i == 0) offs[N] = bsum[B];
}

__global__ void scatter_kernel(const int* __restrict__ row, const int* __restrict__ col,
                               int* __restrict__ cur, int* __restrict__ ccol, int E, int N){
  int stride = gridDim.x * blockDim.x;
  for (int e = blockIdx.x * blockDim.x + threadIdx.x; e < E; e += stride) {
    int r = row[e];
    if ((u32)r >= (u32)N) continue;
    int pos = atomicAdd(&cur[r], 1);
    if ((u32)pos < (u32)E) ccol[pos] = col[e];
  }
}

// One wave per node; each 16-lane quad owns one edge (4 in flight).
__global__ __launch_bounds__(256) void edge_kernel(const void* __restrict__ headp,
                                                   int head_is_bf16,
                                                   const u32* __restrict__ fac,
                                                   const int* __restrict__ offs,
                                                   const int* __restrict__ ccol,
                                                   float* __restrict__ outp, int N, int E){
  int lane = threadIdx.x & 63;
  int n = blockIdx.x * 4 + (threadIdx.x >> 6);
  if (n >= N) return;
  int q = lane >> 4, k = lane & 15;
  float h[8];
  if (head_is_bf16) {
    uint4 hv = *(const uint4*)((const u32*)headp + (size_t)n * ROW_DW + 4 * k);
    h[0] = bf_lo(hv.x); h[1] = bf_hi(hv.x); h[2] = bf_lo(hv.y); h[3] = bf_hi(hv.y);
    h[4] = bf_lo(hv.z); h[5] = bf_hi(hv.z); h[6] = bf_lo(hv.w); h[7] = bf_hi(hv.w);
  } else {
    const float* hp = (const float*)headp + (size_t)n * DIM + 8 * k;
    float4 x0 = *(const float4*)hp, x1 = *(const float4*)(hp + 4);
    h[0] = x0.x; h[1] = x0.y; h[2] = x0.z; h[3] = x0.w;
    h[4] = x1.x; h[5] = x1.y; h[6] = x1.z; h[7] = x1.w;
  }
  float a[8];
#pragma unroll
  for (int j = 0; j < 8; ++j) a[j] = 0.f;
  int beg = offs[n], end = offs[n + 1];
  if (beg < 0) beg = 0;
  if (end > E) end = E;
  for (int e0 = beg; e0 < end; e0 += 4) {
    int e = e0 + q;
    int valid = (e < end) ? 1 : 0;
    int c = valid ? ccol[e] : 0;
    if ((u32)c >= (u32)N) c = 0;
    uint4 tv = *(const uint4*)(fac + (size_t)c * ROW_DW + 4 * k);
    float t[8];
    t[0] = bf_lo(tv.x); t[1] = bf_hi(tv.x); t[2] = bf_lo(tv.y); t[3] = bf_hi(tv.y);
    t[4] = bf_lo(tv.z); t[5] = bf_hi(tv.z); t[6] = bf_lo(tv.w); t[7] = bf_hi(tv.w);
    float dp = 0.f;
#pragma unroll
    for (int j = 0; j < 8; ++j) dp = fmaf(h[j], t[j], dp);
    dp += __shfl_xor(dp, 1); dp += __shfl_xor(dp, 2);   // dot of factor k>>2, edge q
    float d1 = __shfl_xor(dp, 4);
    float d2 = __shfl_xor(dp, 8);
    float d3 = __shfl_xor(d1, 8);                       // all 4 factor dots
    float mx = fmaxf(fmaxf(dp, d1), fmaxf(d2, d3));
    float ex = __expf(dp - mx);
    float es = ex + __expf(d1 - mx) + __expf(d2 - mx) + __expf(d3 - mx);
    float p = valid ? (ex / es) : 0.f;
#pragma unroll
    for (int j = 0; j < 8; ++j) a[j] = fmaf(p, t[j], a[j]);
  }
#pragma unroll
  for (int j = 0; j < 8; ++j) {                         // merge the 4 edge-slots
    a[j] += __shfl_xor(a[j], 16);
    a[j] += __shfl_xor(a[j], 32);
  }
  uint4 fv = *(const uint4*)(fac + (size_t)n * ROW_DW + 4 * k);
  a[0] += bf_lo(fv.x); a[1] += bf_hi(fv.x); a[2] += bf_lo(fv.y); a[3] += bf_hi(fv.y);
  a[4] += bf_lo(fv.z); a[5] += bf_hi(fv.z); a[6] += bf_lo(fv.w); a[7] += bf_hi(fv.w);
  float ss = 0.f;
#pragma unroll
  for (int j = 0; j < 8; ++j) ss = fmaf(a[j], a[j], ss);
  ss += __shfl_xor(ss, 1); ss += __shfl_xor(ss, 2);     // per-factor (4-lane group)
  float inv = 1.0f / fmaxf(sqrtf(ss), 1e-12f);
  if (q == 0) {
    float* op = outp + (size_t)n * DIM + 8 * k;
    *(float4*)op       = make_float4(a[0] * inv, a[1] * inv, a[2] * inv, a[3] * inv);
    *(float4*)(op + 4) = make_float4(a[4] * inv, a[5] * inv, a[6] * inv, a[7] * inv);
  }
}

extern "C" void kernel_launch(void* const* d_in, const int* in_sizes, int n_in,
                              void* d_out, int out_size, void* d_ws, size_t ws_size,
                              hipStream_t stream) {
  int ie = 0, iw = 1, ib = 2, ir = 3, ic = 4;
  if (n_in == 5) {
    int best = -1, besti = 0;
    for (int i = 0; i < 5; ++i) if (in_sizes[i] > best) { best = in_sizes[i]; besti = i; }
    ie = besti; iw = -1; ib = -1; ir = -1; ic = -1;
    for (int i = 0; i < 5; ++i) {
      if (i == ie) continue;
      if (in_sizes[i] == 16384 && iw < 0) iw = i;
      else if (in_sizes[i] == 128 && ib < 0) ib = i;
      else if (ir < 0) ir = i;
      else ic = i;
    }
    if (iw < 0 || ib < 0 || ir < 0 || ic < 0) { ie = 0; iw = 1; ib = 2; ir = 3; ic = 4; }
  }
  const float* emb = (const float*)d_in[ie];   // (N,128) fp32
  const float* W   = (const float*)d_in[iw];   // (4,128,32) fp32
  const float* B   = (const float*)d_in[ib];   // (4,1,32) fp32
  const int* row   = (const int*)d_in[ir];     // (E,)
  const int* col   = (const int*)d_in[ic];     // (E,)
  int N = in_sizes[ie] / DIM;
  int E = in_sizes[ir];
  float* out = (float*)d_out;                  // (N,128) fp32

  // workspace (~33.3 MB): fac | bfrag | cnt | offs | cur | bsum | ccol
  char* ws = (char*)d_ws;
  u16* fac   = (u16*)ws;                       // N*128 u16 (16B aligned)
  u16* bfrag = fac + (size_t)N * DIM;          // 16384 u16 (32 KB)
  int* cnt   = (int*)(bfrag + 16384);          // N
  int* offs  = cnt + N;                        // N+1
  int* cur   = offs + N + 1;                   // N
  int nb_scan = (N + 1023) / 1024;
  int* bsum  = cur + N;                        // nb_scan+1
  int* ccol  = bsum + nb_scan + 1;             // E

  prep_bfrag_kernel<<<64, 256, 0, stream>>>(W, B, bfrag);
  fac_mfma_kernel<<<(N + 63) / 64, 256, 0, stream>>>(emb, (const short8*)bfrag, fac, N);
  zero_int_kernel<<<(N + 255) / 256, 256, 0, stream>>>(cnt, N);
  hist_kernel<<<1024, 256, 0, stream>>>(row, cnt, E, N);
  scan1_kernel<<<nb_scan, 256, 0, stream>>>(cnt, offs, bsum, N);
  scan2_kernel<<<1, 1024, 0, stream>>>(bsum, nb_scan);
  scan3_kernel<<<(N + 255) / 256, 256, 0, stream>>>(offs, bsum, cur, N, nb_scan);
  scatter_kernel<<<1024, 256, 0, stream>>>(row, col, cur, ccol, E, N);
  // iter 1: head = fac (bf16) -> d_out (fp32); iter 2: head = d_out -> d_out in-place
  edge_kernel<<<(N + 3) / 4, 256, 0, stream>>>(fac, 1, (const u32*)fac, offs, ccol, out, N, E);
  edge_kernel<<<(N + 3) / 4, 256, 0, stream>>>(out, 0, (const u32*)fac, offs, ccol, out, N, E);
}

// Round 9
// 449.161 us; speedup vs baseline: 2.5599x; 1.1352x over previous
//
#include <hip/hip_runtime.h>

typedef unsigned int u32;
typedef unsigned short u16;
typedef __attribute__((ext_vector_type(8))) short short8;   // 8 bf16 (4 VGPRs)
typedef __attribute__((ext_vector_type(4))) float f32x4;    // MFMA acc

#define DIM 128      // 4 factors * 32 cols
#define ROW_DW 64    // fac row = 64 dwords (bf16 pairs)

__device__ __forceinline__ float bf_lo(u32 u){ return __uint_as_float(u << 16); }
__device__ __forceinline__ float bf_hi(u32 u){ return __uint_as_float(u & 0xffff0000u); }
__device__ __forceinline__ u16 f2bf(float x){
  u32 u = __float_as_uint(x);
  return (u16)((u + 0x7fffu + ((u >> 16) & 1u)) >> 16);  // RNE
}

__global__ void zero_int_kernel(int* p, int n){
  int i = blockIdx.x * blockDim.x + threadIdx.x;
  if (i < n) p[i] = 0;
}

// B fragments for mfma_f32_16x16x32_bf16, layout [kt][ct][lane][j]:
// frag = bf16( W[f][d][k] + b[f][k] ) at d = kt*32+(lane>>4)*8+j, c = ct*16+(lane&15)
__global__ void prep_bfrag_kernel(const float* __restrict__ W, const float* __restrict__ B,
                                  u16* __restrict__ frag){
  int i = blockIdx.x * 256 + threadIdx.x;       // 4*8*64*8 = 16384
  if (i >= 16384) return;
  int j = i & 7, lane = (i >> 3) & 63, ct = (i >> 9) & 7, kt = i >> 12;
  int d = kt * 32 + (lane >> 4) * 8 + j;
  int c = ct * 16 + (lane & 15);
  int f = c >> 5, k = c & 31;
  frag[i] = f2bf(W[f * 4096 + d * 32 + k] + B[f * 32 + k]);  // W:(4,128,32) b:(4,1,32)
}

// fac = l2norm_f(leaky(emb @ wb)) via MFMA. Wave handles 16 nodes x 128 cols.
__global__ __launch_bounds__(256) void fac_mfma_kernel(const float* __restrict__ emb,
                                                       const short8* __restrict__ bfrag,
                                                       u16* __restrict__ fac, int N){
  int lane = threadIdx.x & 63;
  int nb = blockIdx.x * 64 + (threadIdx.x >> 6) * 16;
  if (nb >= N) return;
  int quad = lane >> 4, lo = lane & 15;
  int arow = nb + lo; if (arow >= N) arow = N - 1;
  const float* ap = emb + (size_t)arow * DIM + quad * 8;
  f32x4 acc[8];
#pragma unroll
  for (int ct = 0; ct < 8; ++ct) acc[ct] = (f32x4){0.f, 0.f, 0.f, 0.f};
#pragma unroll
  for (int kt = 0; kt < 4; ++kt) {
    float4 e0 = *(const float4*)(ap + kt * 32);
    float4 e1 = *(const float4*)(ap + kt * 32 + 4);
    short8 afr;
    afr[0] = (short)f2bf(e0.x); afr[1] = (short)f2bf(e0.y);
    afr[2] = (short)f2bf(e0.z); afr[3] = (short)f2bf(e0.w);
    afr[4] = (short)f2bf(e1.x); afr[5] = (short)f2bf(e1.y);
    afr[6] = (short)f2bf(e1.z); afr[7] = (short)f2bf(e1.w);
#pragma unroll
    for (int ct = 0; ct < 8; ++ct) {
      short8 bfr = bfrag[(kt * 8 + ct) * 64 + lane];
      acc[ct] = __builtin_amdgcn_mfma_f32_16x16x32_bf16(afr, bfr, acc[ct], 0, 0, 0);
    }
  }
  float v[8][4];
#pragma unroll
  for (int ct = 0; ct < 8; ++ct)
#pragma unroll
    for (int i = 0; i < 4; ++i) {
      float x = acc[ct][i];
      v[ct][i] = x > 0.f ? x : 0.2f * x;
    }
  float inv[4][4];   // [i][f]
#pragma unroll
  for (int i = 0; i < 4; ++i)
#pragma unroll
    for (int f = 0; f < 4; ++f) {
      float ss = v[2 * f][i] * v[2 * f][i] + v[2 * f + 1][i] * v[2 * f + 1][i];
      ss += __shfl_xor(ss, 1); ss += __shfl_xor(ss, 2);
      ss += __shfl_xor(ss, 4); ss += __shfl_xor(ss, 8);
      inv[i][f] = 1.0f / fmaxf(sqrtf(ss), 1e-12f);
    }
#pragma unroll
  for (int i = 0; i < 4; ++i) {
    int node = nb + quad * 4 + i;
    if (node >= N) continue;
#pragma unroll
    for (int ct = 0; ct < 8; ++ct)
      fac[(size_t)node * DIM + ct * 16 + lo] = f2bf(v[ct][i] * inv[i][ct >> 1]);
  }
}

// XCD-partitioned histogram: block (b&7) handles rows with part(r)==(b&7);
// partition = min(7, r*8/N) via float scale. Each edge read by 8 sibling
// blocks, counted by exactly one -> cnt atomics stay XCD-local.
__global__ void hist_kernel(const int* __restrict__ row, int* __restrict__ cnt,
                            int E, int N, float pscale){
  int xcd = blockIdx.x & 7;
  int base = (blockIdx.x >> 3) * blockDim.x + threadIdx.x;
  int stride = (gridDim.x >> 3) * blockDim.x;
  for (int e = base; e < E; e += stride) {
    int r = row[e];
    if ((u32)r >= (u32)N) continue;
    int part = (int)((float)r * pscale);
    part = part > 7 ? 7 : part;
    if (part != xcd) continue;
    atomicAdd(&cnt[r], 1);
  }
}

// ---- 3-phase exclusive scan of cnt[0..N) -> offs[0..N], bsum scratch ----
__global__ __launch_bounds__(256) void scan1_kernel(const int* __restrict__ cnt,
                                                    int* __restrict__ offs,
                                                    int* __restrict__ bsum, int N){
  __shared__ int sh[256];
  int tid = threadIdx.x;
  int idx = blockIdx.x * 1024 + tid * 4;
  int v0 = (idx     < N) ? cnt[idx]     : 0;
  int v1 = (idx + 1 < N) ? cnt[idx + 1] : 0;
  int v2 = (idx + 2 < N) ? cnt[idx + 2] : 0;
  int v3 = (idx + 3 < N) ? cnt[idx + 3] : 0;
  sh[tid] = v0 + v1 + v2 + v3;
  __syncthreads();
  for (int off = 1; off < 256; off <<= 1) {
    int v = (tid >= off) ? sh[tid - off] : 0;
    __syncthreads();
    sh[tid] += v;
    __syncthreads();
  }
  int ex = (tid == 0) ? 0 : sh[tid - 1];
  if (tid == 255) bsum[blockIdx.x] = sh[255];
  if (idx     < N) offs[idx]     = ex;
  if (idx + 1 < N) offs[idx + 1] = ex + v0;
  if (idx + 2 < N) offs[idx + 2] = ex + v0 + v1;
  if (idx + 3 < N) offs[idx + 3] = ex + v0 + v1 + v2;
}

__global__ __launch_bounds__(1024) void scan2_kernel(int* __restrict__ bsum, int B){
  __shared__ int sh[1024];
  int tid = threadIdx.x;
  sh[tid] = (tid < B) ? bsum[tid] : 0;
  __syncthreads();
  for (int off = 1; off < 1024; off <<= 1) {
    int v = (tid >= off) ? sh[tid - off] : 0;
    __syncthreads();
    sh[tid] += v;
    __syncthreads();
  }
  if (tid < B) bsum[tid] = (tid == 0) ? 0 : sh[tid - 1];
  if (tid == B - 1) bsum[B] = sh[tid];
}

__global__ void scan3_kernel(int* __restrict__ offs, const int* __restrict__ bsum,
                             int* __restrict__ cur, int N, int B){
  int i = blockIdx.x * blockDim.x + threadIdx.x;
  if (i < N) {
    int v = offs[i] + bsum[i >> 10];
    offs[i] = v;
    cur[i] = v;
  }
  if (i == 0) offs[N] = bsum[B];
}

// XCD-partitioned scatter: same partition function as hist. ccol region for a
// row-range is contiguous -> each 64B ccol line is written by one XCD only,
// accumulating in its L2 (writeback once) instead of 16 amplified writebacks.
__global__ void scatter_kernel(const int* __restrict__ row, const int* __restrict__ col,
                               int* __restrict__ cur, int* __restrict__ ccol,
                               int E, int N, float pscale){
  int xcd = blockIdx.x & 7;
  int base = (blockIdx.x >> 3) * blockDim.x + threadIdx.x;
  int stride = (gridDim.x >> 3) * blockDim.x;
  for (int e = base; e < E; e += stride) {
    int r = row[e];
    if ((u32)r >= (u32)N) continue;
    int part = (int)((float)r * pscale);
    part = part > 7 ? 7 : part;
    if (part != xcd) continue;
    int pos = atomicAdd(&cur[r], 1);
    if ((u32)pos < (u32)E) ccol[pos] = col[e];
  }
}

// One wave per node; each 16-lane quad owns one edge (4 in flight).
__global__ __launch_bounds__(256) void edge_kernel(const void* __restrict__ headp,
                                                   int head_is_bf16,
                                                   const u32* __restrict__ fac,
                                                   const int* __restrict__ offs,
                                                   const int* __restrict__ ccol,
                                                   float* __restrict__ outp, int N, int E){
  int lane = threadIdx.x & 63;
  int n = blockIdx.x * 4 + (threadIdx.x >> 6);
  if (n >= N) return;
  int q = lane >> 4, k = lane & 15;
  float h[8];
  if (head_is_bf16) {
    uint4 hv = *(const uint4*)((const u32*)headp + (size_t)n * ROW_DW + 4 * k);
    h[0] = bf_lo(hv.x); h[1] = bf_hi(hv.x); h[2] = bf_lo(hv.y); h[3] = bf_hi(hv.y);
    h[4] = bf_lo(hv.z); h[5] = bf_hi(hv.z); h[6] = bf_lo(hv.w); h[7] = bf_hi(hv.w);
  } else {
    const float* hp = (const float*)headp + (size_t)n * DIM + 8 * k;
    float4 x0 = *(const float4*)hp, x1 = *(const float4*)(hp + 4);
    h[0] = x0.x; h[1] = x0.y; h[2] = x0.z; h[3] = x0.w;
    h[4] = x1.x; h[5] = x1.y; h[6] = x1.z; h[7] = x1.w;
  }
  float a[8];
#pragma unroll
  for (int j = 0; j < 8; ++j) a[j] = 0.f;
  int beg = offs[n], end = offs[n + 1];
  if (beg < 0) beg = 0;
  if (end > E) end = E;
  for (int e0 = beg; e0 < end; e0 += 4) {
    int e = e0 + q;
    int valid = (e < end) ? 1 : 0;
    int c = valid ? ccol[e] : 0;
    if ((u32)c >= (u32)N) c = 0;
    uint4 tv = *(const uint4*)(fac + (size_t)c * ROW_DW + 4 * k);
    float t[8];
    t[0] = bf_lo(tv.x); t[1] = bf_hi(tv.x); t[2] = bf_lo(tv.y); t[3] = bf_hi(tv.y);
    t[4] = bf_lo(tv.z); t[5] = bf_hi(tv.z); t[6] = bf_lo(tv.w); t[7] = bf_hi(tv.w);
    float dp = 0.f;
#pragma unroll
    for (int j = 0; j < 8; ++j) dp = fmaf(h[j], t[j], dp);
    dp += __shfl_xor(dp, 1); dp += __shfl_xor(dp, 2);   // dot of factor k>>2, edge q
    float d1 = __shfl_xor(dp, 4);
    float d2 = __shfl_xor(dp, 8);
    float d3 = __shfl_xor(d1, 8);                       // all 4 factor dots
    float mx = fmaxf(fmaxf(dp, d1), fmaxf(d2, d3));
    float ex = __expf(dp - mx);
    float es = ex + __expf(d1 - mx) + __expf(d2 - mx) + __expf(d3 - mx);
    float p = valid ? (ex / es) : 0.f;
#pragma unroll
    for (int j = 0; j < 8; ++j) a[j] = fmaf(p, t[j], a[j]);
  }
#pragma unroll
  for (int j = 0; j < 8; ++j) {                         // merge the 4 edge-slots
    a[j] += __shfl_xor(a[j], 16);
    a[j] += __shfl_xor(a[j], 32);
  }
  uint4 fv = *(const uint4*)(fac + (size_t)n * ROW_DW + 4 * k);
  a[0] += bf_lo(fv.x); a[1] += bf_hi(fv.x); a[2] += bf_lo(fv.y); a[3] += bf_hi(fv.y);
  a[4] += bf_lo(fv.z); a[5] += bf_hi(fv.z); a[6] += bf_lo(fv.w); a[7] += bf_hi(fv.w);
  float ss = 0.f;
#pragma unroll
  for (int j = 0; j < 8; ++j) ss = fmaf(a[j], a[j], ss);
  ss += __shfl_xor(ss, 1); ss += __shfl_xor(ss, 2);     // per-factor (4-lane group)
  float inv = 1.0f / fmaxf(sqrtf(ss), 1e-12f);
  if (q == 0) {
    float* op = outp + (size_t)n * DIM + 8 * k;
    *(float4*)op       = make_float4(a[0] * inv, a[1] * inv, a[2] * inv, a[3] * inv);
    *(float4*)(op + 4) = make_float4(a[4] * inv, a[5] * inv, a[6] * inv, a[7] * inv);
  }
}

extern "C" void kernel_launch(void* const* d_in, const int* in_sizes, int n_in,
                              void* d_out, int out_size, void* d_ws, size_t ws_size,
                              hipStream_t stream) {
  int ie = 0, iw = 1, ib = 2, ir = 3, ic = 4;
  if (n_in == 5) {
    int best = -1, besti = 0;
    for (int i = 0; i < 5; ++i) if (in_sizes[i] > best) { best = in_sizes[i]; besti = i; }
    ie = besti; iw = -1; ib = -1; ir = -1; ic = -1;
    for (int i = 0; i < 5; ++i) {
      if (i == ie) continue;
      if (in_sizes[i] == 16384 && iw < 0) iw = i;
      else if (in_sizes[i] == 128 && ib < 0) ib = i;
      else if (ir < 0) ir = i;
      else ic = i;
    }
    if (iw < 0 || ib < 0 || ir < 0 || ic < 0) { ie = 0; iw = 1; ib = 2; ir = 3; ic = 4; }
  }
  const float* emb = (const float*)d_in[ie];   // (N,128) fp32
  const float* W   = (const float*)d_in[iw];   // (4,128,32) fp32
  const float* B   = (const float*)d_in[ib];   // (4,1,32) fp32
  const int* row   = (const int*)d_in[ir];     // (E,)
  const int* col   = (const int*)d_in[ic];     // (E,)
  int N = in_sizes[ie] / DIM;
  int E = in_sizes[ir];
  float* out = (float*)d_out;                  // (N,128) fp32
  float pscale = 8.0f / (float)N;              // row -> XCD partition (any consistent fn)

  // workspace (~33.3 MB): fac | bfrag | cnt | offs | cur | bsum | ccol
  char* ws = (char*)d_ws;
  u16* fac   = (u16*)ws;                       // N*128 u16 (16B aligned)
  u16* bfrag = fac + (size_t)N * DIM;          // 16384 u16 (32 KB)
  int* cnt   = (int*)(bfrag + 16384);          // N
  int* offs  = cnt + N;                        // N+1
  int* cur   = offs + N + 1;                   // N
  int nb_scan = (N + 1023) / 1024;
  int* bsum  = cur + N;                        // nb_scan+1
  int* ccol  = bsum + nb_scan + 1;             // E

  prep_bfrag_kernel<<<64, 256, 0, stream>>>(W, B, bfrag);
  fac_mfma_kernel<<<(N + 63) / 64, 256, 0, stream>>>(emb, (const short8*)bfrag, fac, N);
  zero_int_kernel<<<(N + 255) / 256, 256, 0, stream>>>(cnt, N);
  hist_kernel<<<2048, 256, 0, stream>>>(row, cnt, E, N, pscale);
  scan1_kernel<<<nb_scan, 256, 0, stream>>>(cnt, offs, bsum, N);
  scan2_kernel<<<1, 1024, 0, stream>>>(bsum, nb_scan);
  scan3_kernel<<<(N + 255) / 256, 256, 0, stream>>>(offs, bsum, cur, N, nb_scan);
  scatter_kernel<<<2048, 256, 0, stream>>>(row, col, cur, ccol, E, N, pscale);
  // iter 1: head = fac (bf16) -> d_out (fp32); iter 2: head = d_out -> d_out in-place
  edge_kernel<<<(N + 3) / 4, 256, 0, stream>>>(fac, 1, (const u32*)fac, offs, ccol, out, N, E);
  edge_kernel<<<(N + 3) / 4, 256, 0, stream>>>(out, 0, (const u32*)fac, offs, ccol, out, N, E);
}